// Round 2
// baseline (165.380 us; speedup 1.0000x reference)
//
#include <hip/hip_runtime.h>

#define EPS2 1e-16f

constexpr int H    = 64;
constexpr int FIN  = 7;
constexpr int FOUT = 4;
constexpr int BLOCK = 256;
constexpr int NCHUNK = 4; // sources per thread (S=1024 / 256)

__device__ __forceinline__ float fast_sigmoid(float x) {
    return 1.0f / (1.0f + __expf(-x));
}

__device__ __forceinline__ float fast_tanh(float x) {
    float cx = fminf(fmaxf(x, -15.0f), 15.0f);
    float e = __expf(2.0f * cx);
    return (e - 1.0f) / (e + 1.0f);
}

__global__ __launch_bounds__(BLOCK)
void bh_kernel(const float* __restrict__ refLenP,
               const float* __restrict__ srcP,   // (S,3)
               const float* __restrict__ tgtP,   // (T,3)
               const float* __restrict__ wgtP,   // (S,)
               const float* __restrict__ areaP,  // (S,)
               const float* __restrict__ srcN,   // (S,3)
               const float* __restrict__ W1,     // (7,64)
               const float* __restrict__ b1,     // (64,)
               const float* __restrict__ W2,     // (64,4)
               const float* __restrict__ b2,     // (4,)
               float* __restrict__ out,          // (T,4)
               int S)
{
    __shared__ float sW1[FIN * H];
    __shared__ float sb1[H];
    __shared__ float sW2[H * FOUT];
    __shared__ float red[4][4];

    const int tid = threadIdx.x;

    // Stage weights into LDS (broadcast-read later; conflict-free).
    for (int i = tid; i < FIN * H; i += BLOCK) sW1[i] = W1[i];
    if (tid < H) sb1[tid] = b1[tid];
    for (int i = tid; i < H * FOUT; i += BLOCK) sW2[i] = W2[i];
    __syncthreads();

    const int t = blockIdx.x;
    const float invL = 1.0f / refLenP[0];
    const float tx = tgtP[t * 3 + 0];
    const float ty = tgtP[t * 3 + 1];
    const float tz = tgtP[t * 3 + 2];

    float feats[NCHUNK][FIN];
    float ws_s[NCHUNK];                       // w * inv_r
    float wv_s[NCHUNK];                       // w * inv_r^2
    float rhx[NCHUNK], rhy[NCHUNK], rhz[NCHUNK];
    float nhx[NCHUNK], nhy[NCHUNK], nhz[NCHUNK];

    // Phase A: per-source geometry + features into registers.
    #pragma unroll
    for (int c = 0; c < NCHUNK; ++c) {
        const int s = tid + c * BLOCK;
        if (s < S) {
            float sx = srcP[s * 3 + 0], sy = srcP[s * 3 + 1], sz = srcP[s * 3 + 2];
            float nx = srcN[s * 3 + 0], ny = srcN[s * 3 + 1], nz = srcN[s * 3 + 2];
            float rx = (tx - sx) * invL;
            float ry = (ty - sy) * invL;
            float rz = (tz - sz) * invL;
            float r2 = fmaf(rx, rx, fmaf(ry, ry, rz * rz)) + EPS2;
            float n2 = fmaf(nx, nx, fmaf(ny, ny, nz * nz)) + EPS2;
            float inv_r = rsqrtf(r2);
            float inv_n = rsqrtf(n2);
            float log_r = 0.5f * __logf(r2);
            float log_n = 0.5f * __logf(n2);
            float cosv = fmaf(rx, nx, fmaf(ry, ny, rz * nz)) * inv_r * inv_n;
            float c2 = cosv * cosv;
            feats[c][0] = areaP[s];
            feats[c][1] = log_r;
            feats[c][2] = log_n;
            feats[c][3] = cosv;                                   // P1
            feats[c][4] = fmaf(1.5f, c2, -0.5f);                  // P2
            feats[c][5] = (2.5f * c2 - 1.5f) * cosv;              // P3
            feats[c][6] = fmaf(fmaf(4.375f, c2, -3.75f), c2, 0.375f); // P4
            float w = wgtP[s];
            ws_s[c] = w * inv_r;
            wv_s[c] = w * inv_r * inv_r;
            rhx[c] = rx * inv_r; rhy[c] = ry * inv_r; rhz[c] = rz * inv_r;
            nhx[c] = nx * inv_n; nhy[c] = ny * inv_n; nhz[c] = nz * inv_n;
        } else {
            #pragma unroll
            for (int f = 0; f < FIN; ++f) feats[c][f] = 0.0f;
            ws_s[c] = 0.0f; wv_s[c] = 0.0f;
            rhx[c] = rhy[c] = rhz[c] = 0.0f;
            nhx[c] = nhy[c] = nhz[c] = 0.0f;
        }
    }

    // Phase B: fused MLP (layer1 silu + layer2 accumulate), weights amortized
    // over the 4 per-thread sources.
    float o[NCHUNK][FOUT];
    {
        float bb0 = b2[0], bb1 = b2[1], bb2 = b2[2], bb3 = b2[3];
        #pragma unroll
        for (int c = 0; c < NCHUNK; ++c) {
            o[c][0] = bb0; o[c][1] = bb1; o[c][2] = bb2; o[c][3] = bb3;
        }
    }

    #pragma unroll 8
    for (int h = 0; h < H; ++h) {
        float wcol[FIN];
        #pragma unroll
        for (int f = 0; f < FIN; ++f) wcol[f] = sW1[f * H + h];
        const float bb  = sb1[h];
        const float w20 = sW2[h * FOUT + 0];
        const float w21 = sW2[h * FOUT + 1];
        const float w22 = sW2[h * FOUT + 2];
        const float w23 = sW2[h * FOUT + 3];
        #pragma unroll
        for (int c = 0; c < NCHUNK; ++c) {
            float a = bb;
            #pragma unroll
            for (int f = 0; f < FIN; ++f) a = fmaf(feats[c][f], wcol[f], a);
            float hv = a * fast_sigmoid(a);
            o[c][0] = fmaf(hv, w20, o[c][0]);
            o[c][1] = fmaf(hv, w21, o[c][1]);
            o[c][2] = fmaf(hv, w22, o[c][2]);
            o[c][3] = fmaf(hv, w23, o[c][3]);
        }
    }

    // Phase C: epilogue — tanh, cross product, weighted accumulation.
    float acc0 = 0.0f, acc1 = 0.0f, acc2 = 0.0f, acc3 = 0.0f;
    #pragma unroll
    for (int c = 0; c < NCHUNK; ++c) {
        float o0 = fast_tanh(o[c][0]);
        float o1 = fast_tanh(o[c][1]);
        float o2 = fast_tanh(o[c][2]);
        float o3 = fast_tanh(o[c][3]);
        acc0 = fmaf(ws_s[c], o0, acc0);
        float cxx = rhy[c] * nhz[c] - rhz[c] * nhy[c];
        float cxy = rhz[c] * nhx[c] - rhx[c] * nhz[c];
        float cxz = rhx[c] * nhy[c] - rhy[c] * nhx[c];
        float vx = o1 * rhx[c] + o2 * nhx[c] + o3 * cxx;
        float vy = o1 * rhy[c] + o2 * nhy[c] + o3 * cxy;
        float vz = o1 * rhz[c] + o2 * nhz[c] + o3 * cxz;
        acc1 = fmaf(wv_s[c], vx, acc1);
        acc2 = fmaf(wv_s[c], vy, acc2);
        acc3 = fmaf(wv_s[c], vz, acc3);
    }

    // Phase D: block reduction (wave shuffle, then LDS across 4 waves).
    #pragma unroll
    for (int off = 32; off > 0; off >>= 1) {
        acc0 += __shfl_down(acc0, off);
        acc1 += __shfl_down(acc1, off);
        acc2 += __shfl_down(acc2, off);
        acc3 += __shfl_down(acc3, off);
    }
    const int wave = tid >> 6;
    const int lane = tid & 63;
    if (lane == 0) {
        red[wave][0] = acc0; red[wave][1] = acc1;
        red[wave][2] = acc2; red[wave][3] = acc3;
    }
    __syncthreads();
    if (tid < 4) {
        float v = red[0][tid] + red[1][tid] + red[2][tid] + red[3][tid];
        out[t * 4 + tid] = v;
    }
}

extern "C" void kernel_launch(void* const* d_in, const int* in_sizes, int n_in,
                              void* d_out, int out_size, void* d_ws, size_t ws_size,
                              hipStream_t stream) {
    const float* refLen = (const float*)d_in[0];
    const float* srcP   = (const float*)d_in[1];
    const float* tgtP   = (const float*)d_in[2];
    const float* w      = (const float*)d_in[3];
    const float* area   = (const float*)d_in[4];
    const float* srcN   = (const float*)d_in[5];
    const float* W1     = (const float*)d_in[6];
    const float* b1     = (const float*)d_in[7];
    const float* W2     = (const float*)d_in[8];
    const float* b2     = (const float*)d_in[9];
    float* out          = (float*)d_out;

    const int S = in_sizes[3];
    const int T = in_sizes[2] / 3;

    bh_kernel<<<T, BLOCK, 0, stream>>>(refLen, srcP, tgtP, w, area, srcN,
                                       W1, b1, W2, b2, out, S);
}

// Round 3
// 124.049 us; speedup vs baseline: 1.3332x; 1.3332x over previous
//
#include <hip/hip_runtime.h>

typedef float v2f __attribute__((ext_vector_type(2)));

#define EPS2 1e-16f

constexpr int H     = 64;
constexpr int FIN   = 7;
constexpr int FOUT  = 4;
constexpr int BLOCK = 256;
constexpr int NCHUNK = 4;           // sources per thread (S=1024 / 256)
constexpr int NV     = NCHUNK / 2;  // v2f groups

__device__ __forceinline__ float rcpf_fast(float x) { return __builtin_amdgcn_rcpf(x); }
__device__ __forceinline__ float rsqf_fast(float x) { return __builtin_amdgcn_rsqf(x); }
__device__ __forceinline__ v2f splat(float x) { return v2f{x, x}; }
__device__ __forceinline__ v2f vfma(v2f a, v2f b, v2f c) { return __builtin_elementwise_fma(a, b, c); }

__device__ __forceinline__ float tanhf_fast(float x) {
    float cx = fminf(fmaxf(x, -15.0f), 15.0f);
    float e = __expf(2.0f * cx);
    return (e - 1.0f) * rcpf_fast(e + 1.0f);
}
__device__ __forceinline__ v2f tanhv(v2f x) {
    return v2f{tanhf_fast(x.x), tanhf_fast(x.y)};
}

__global__ __launch_bounds__(BLOCK, 2)
void bh_kernel(const float* __restrict__ refLenP,
               const float* __restrict__ srcP,   // (S,3)
               const float* __restrict__ tgtP,   // (T,3)
               const float* __restrict__ wgtP,   // (S,)
               const float* __restrict__ areaP,  // (S,)
               const float* __restrict__ srcN,   // (S,3)
               const float* __restrict__ W1,     // (7,64)
               const float* __restrict__ b1,     // (64,)
               const float* __restrict__ W2,     // (64,4)
               const float* __restrict__ b2,     // (4,)
               float* __restrict__ out,          // (T,4)
               int S)
{
    // sW1t[h*8 + f] = W1[f][h] for f<7, b1[h] for f==7  -> 2x ds_read_b128 per h
    __shared__ float sW1t[H * 8];
    __shared__ float sW2[H * FOUT];   // row-major (h,4) -> 1x ds_read_b128 per h
    __shared__ float red[4][4];

    const int tid = threadIdx.x;

    for (int i = tid; i < H * 8; i += BLOCK) {
        int h = i >> 3, f = i & 7;
        sW1t[i] = (f < FIN) ? W1[f * H + h] : b1[h];
    }
    for (int i = tid; i < H * FOUT; i += BLOCK) sW2[i] = W2[i];
    __syncthreads();

    const int t = blockIdx.x;
    const float invL = rcpf_fast(refLenP[0]);
    const float tx = tgtP[t * 3 + 0];
    const float ty = tgtP[t * 3 + 1];
    const float tz = tgtP[t * 3 + 2];

    v2f feats[NV][FIN];
    v2f ws_s[NV], wv_s[NV];
    v2f rhx[NV], rhy[NV], rhz[NV];
    v2f nhx[NV], nhy[NV], nhz[NV];

    // Phase A: geometry + features (packed pairs of chunks).
    #pragma unroll
    for (int v = 0; v < NV; ++v) {
        const int sA = tid + (2 * v) * BLOCK;
        const int sB = sA + BLOCK;
        const int cA = (sA < S) ? sA : (S - 1);
        const int cB = (sB < S) ? sB : (S - 1);
        const float wA = (sA < S) ? wgtP[cA] : 0.0f;
        const float wB = (sB < S) ? wgtP[cB] : 0.0f;

        v2f rx = v2f{(tx - srcP[cA * 3 + 0]) * invL, (tx - srcP[cB * 3 + 0]) * invL};
        v2f ry = v2f{(ty - srcP[cA * 3 + 1]) * invL, (ty - srcP[cB * 3 + 1]) * invL};
        v2f rz = v2f{(tz - srcP[cA * 3 + 2]) * invL, (tz - srcP[cB * 3 + 2]) * invL};
        v2f nx = v2f{srcN[cA * 3 + 0], srcN[cB * 3 + 0]};
        v2f ny = v2f{srcN[cA * 3 + 1], srcN[cB * 3 + 1]};
        v2f nz = v2f{srcN[cA * 3 + 2], srcN[cB * 3 + 2]};

        v2f r2 = vfma(rx, rx, vfma(ry, ry, rz * rz)) + splat(EPS2);
        v2f n2 = vfma(nx, nx, vfma(ny, ny, nz * nz)) + splat(EPS2);
        v2f inv_r = v2f{rsqf_fast(r2.x), rsqf_fast(r2.y)};
        v2f inv_n = v2f{rsqf_fast(n2.x), rsqf_fast(n2.y)};
        v2f log_r = v2f{__logf(r2.x), __logf(r2.y)} * splat(0.5f);
        v2f log_n = v2f{__logf(n2.x), __logf(n2.y)} * splat(0.5f);
        v2f cosv = vfma(rx, nx, vfma(ry, ny, rz * nz)) * inv_r * inv_n;
        v2f c2 = cosv * cosv;

        feats[v][0] = v2f{(sA < S) ? areaP[cA] : 0.0f, (sB < S) ? areaP[cB] : 0.0f};
        feats[v][1] = log_r;
        feats[v][2] = log_n;
        feats[v][3] = cosv;
        feats[v][4] = vfma(c2, splat(1.5f), splat(-0.5f));
        feats[v][5] = (c2 * splat(2.5f) - splat(1.5f)) * cosv;
        feats[v][6] = vfma(vfma(c2, splat(4.375f), splat(-3.75f)), c2, splat(0.375f));

        v2f w = v2f{wA, wB};
        ws_s[v] = w * inv_r;
        wv_s[v] = w * inv_r * inv_r;
        rhx[v] = rx * inv_r; rhy[v] = ry * inv_r; rhz[v] = rz * inv_r;
        nhx[v] = nx * inv_n; nhy[v] = ny * inv_n; nhz[v] = nz * inv_n;
    }

    // Phase B: fused MLP. 8 pk-FMA + 2 exp + 2 rcp + 5 pk ops per (h, v).
    v2f o0[NV], o1[NV], o2[NV], o3[NV];
    {
        const float bb0 = b2[0], bb1 = b2[1], bb2 = b2[2], bb3 = b2[3];
        #pragma unroll
        for (int v = 0; v < NV; ++v) {
            o0[v] = splat(bb0); o1[v] = splat(bb1);
            o2[v] = splat(bb2); o3[v] = splat(bb3);
        }
    }

    #pragma unroll 8
    for (int h = 0; h < H; ++h) {
        const float4 wa = *reinterpret_cast<const float4*>(&sW1t[h * 8]);
        const float4 wb = *reinterpret_cast<const float4*>(&sW1t[h * 8 + 4]);
        const float4 w2 = *reinterpret_cast<const float4*>(&sW2[h * 4]);
        #pragma unroll
        for (int v = 0; v < NV; ++v) {
            v2f a = splat(wb.w);  // b1[h]
            a = vfma(feats[v][0], splat(wa.x), a);
            a = vfma(feats[v][1], splat(wa.y), a);
            a = vfma(feats[v][2], splat(wa.z), a);
            a = vfma(feats[v][3], splat(wa.w), a);
            a = vfma(feats[v][4], splat(wb.x), a);
            a = vfma(feats[v][5], splat(wb.y), a);
            a = vfma(feats[v][6], splat(wb.z), a);
            // silu(a) = a * sigmoid(a) = a * rcp(1 + exp(-a))
            v2f e  = v2f{__expf(-a.x), __expf(-a.y)};
            v2f sg = v2f{rcpf_fast(1.0f + e.x), rcpf_fast(1.0f + e.y)};
            v2f hv = a * sg;
            o0[v] = vfma(hv, splat(w2.x), o0[v]);
            o1[v] = vfma(hv, splat(w2.y), o1[v]);
            o2[v] = vfma(hv, splat(w2.z), o2[v]);
            o3[v] = vfma(hv, splat(w2.w), o3[v]);
        }
    }

    // Phase C: epilogue — tanh, cross, weighted accumulation (packed).
    v2f a0 = splat(0.0f), a1 = splat(0.0f), a2 = splat(0.0f), a3 = splat(0.0f);
    #pragma unroll
    for (int v = 0; v < NV; ++v) {
        v2f t0 = tanhv(o0[v]);
        v2f t1 = tanhv(o1[v]);
        v2f t2 = tanhv(o2[v]);
        v2f t3 = tanhv(o3[v]);
        a0 = vfma(ws_s[v], t0, a0);
        v2f cxx = rhy[v] * nhz[v] - rhz[v] * nhy[v];
        v2f cxy = rhz[v] * nhx[v] - rhx[v] * nhz[v];
        v2f cxz = rhx[v] * nhy[v] - rhy[v] * nhx[v];
        v2f vx = t1 * rhx[v] + t2 * nhx[v] + t3 * cxx;
        v2f vy = t1 * rhy[v] + t2 * nhy[v] + t3 * cxy;
        v2f vz = t1 * rhz[v] + t2 * nhz[v] + t3 * cxz;
        a1 = vfma(wv_s[v], vx, a1);
        a2 = vfma(wv_s[v], vy, a2);
        a3 = vfma(wv_s[v], vz, a3);
    }
    float acc0 = a0.x + a0.y;
    float acc1 = a1.x + a1.y;
    float acc2 = a2.x + a2.y;
    float acc3 = a3.x + a3.y;

    // Phase D: block reduction (wave shuffle, then LDS across 4 waves).
    #pragma unroll
    for (int off = 32; off > 0; off >>= 1) {
        acc0 += __shfl_down(acc0, off);
        acc1 += __shfl_down(acc1, off);
        acc2 += __shfl_down(acc2, off);
        acc3 += __shfl_down(acc3, off);
    }
    const int wave = tid >> 6;
    const int lane = tid & 63;
    if (lane == 0) {
        red[wave][0] = acc0; red[wave][1] = acc1;
        red[wave][2] = acc2; red[wave][3] = acc3;
    }
    __syncthreads();
    if (tid < 4) {
        float v = red[0][tid] + red[1][tid] + red[2][tid] + red[3][tid];
        out[t * 4 + tid] = v;
    }
}

extern "C" void kernel_launch(void* const* d_in, const int* in_sizes, int n_in,
                              void* d_out, int out_size, void* d_ws, size_t ws_size,
                              hipStream_t stream) {
    const float* refLen = (const float*)d_in[0];
    const float* srcP   = (const float*)d_in[1];
    const float* tgtP   = (const float*)d_in[2];
    const float* w      = (const float*)d_in[3];
    const float* area   = (const float*)d_in[4];
    const float* srcN   = (const float*)d_in[5];
    const float* W1     = (const float*)d_in[6];
    const float* b1     = (const float*)d_in[7];
    const float* W2     = (const float*)d_in[8];
    const float* b2     = (const float*)d_in[9];
    float* out          = (float*)d_out;

    const int S = in_sizes[3];
    const int T = in_sizes[2] / 3;

    bh_kernel<<<T, BLOCK, 0, stream>>>(refLen, srcP, tgtP, w, area, srcN,
                                       W1, b1, W2, b2, out, S);
}